// Round 6
// baseline (304.709 us; speedup 1.0000x reference)
//
#include <hip/hip_runtime.h>
#include <cstdint>

#define NIMG 8
#define PRE 2000
#define POST 1000
#define NCH 128                   // candidate chunks per image (one per compact block)
#define CH_CAP 128                // entries per chunk
#define CAND_TOT (NCH*CH_CAP)     // 16384 slots per image
#define NSORT 4                   // sorter blocks per image
#define GPS (NCH/NSORT)           // 32 chunks gathered per sorter block
#define SEG 2048                  // sorted segment length
#define CAND_MAX (NSORT*SEG)      // 8192 candidates usable
#define NPB 64                    // pair-tile blocks per image
#define PB_CAP 1024               // pairs per tile block
#define PAIR_CAP 12288            // k_final LDS pair cap
#define JT 256                    // pair tile edge
#define IMGW 800.0f
#define BBOX_CLIP_F 4.135166556742356f
// fkey(2.5f): fast-path static threshold. count(logit>=2.5) ~ 6210+-79 per image
// -> >=PRE and group sums <=SEG with >>10 sigma margin. Exact in-kernel fallback otherwise.
#define STATIC_KMIN 0xC0200000u

// workspace layout (bytes) -- no pre-zeroing needed anywhere
#define OFF_BCNT  0
#define OFF_DONE  (OFF_BCNT + NIMG*NCH*4)          // 8 flags @ 128B stride
#define OFF_BPCNT (OFF_DONE + 1024)
#define OFF_CAND  (OFF_BPCNT + NIMG*NPB*4)
#define OFF_SRT   (OFF_CAND + (size_t)NIMG*CAND_TOT*8)
#define OFF_BOX   (OFF_SRT + (size_t)NIMG*CAND_MAX*8)
#define OFF_SCORE (OFF_BOX + (size_t)NIMG*PRE*16)
#define OFF_VALID (OFF_SCORE + NIMG*PRE*4)
#define OFF_PAIRS (OFF_VALID + NIMG*PRE*4)

__device__ __forceinline__ unsigned int fkey(float f) {
    unsigned int b = __float_as_uint(f);
    return (b & 0x80000000u) ? ~b : (b | 0x80000000u);   // monotone float->uint
}
__device__ __forceinline__ float inv_fkey(unsigned int k) {
    unsigned int b = (k & 0x80000000u) ? (k ^ 0x80000000u) : ~k;
    return __uint_as_float(b);
}

// single 32MB pass: static-threshold compact into per-block private chunks (no global atomics);
// also zeroes the per-image done flags used by k_sortmerge's intra-kernel sync.
__global__ void k_compact(const float* __restrict__ obj,
                          unsigned long long* __restrict__ cand,
                          unsigned int* __restrict__ bcnt,
                          unsigned int* __restrict__ done, int A) {
    __shared__ unsigned long long loc[CH_CAP];
    __shared__ unsigned int lcnt;
    const int img = blockIdx.y;
    const int b = blockIdx.x;
    const int t = threadIdx.x;
    if (t == 0) {
        lcnt = 0u;
        if (b == 0) done[img * 32] = 0u;
    }
    __syncthreads();
    const float4* p4 = (const float4*)(obj + (size_t)img * A);
    const int nvec = A >> 2;
    for (int i = b * 256 + t; i < nvec; i += NCH * 256) {
        float4 v = p4[i];
        unsigned int k0 = fkey(v.x), k1 = fkey(v.y), k2 = fkey(v.z), k3 = fkey(v.w);
        unsigned int base = (unsigned int)(i << 2);
        if (k0 >= STATIC_KMIN) { unsigned int p = atomicAdd(&lcnt, 1u); if (p < CH_CAP) loc[p] = ((unsigned long long)k0 << 32) | (0xFFFFFFFFu - base); }
        if (k1 >= STATIC_KMIN) { unsigned int p = atomicAdd(&lcnt, 1u); if (p < CH_CAP) loc[p] = ((unsigned long long)k1 << 32) | (0xFFFFFFFFu - (base + 1u)); }
        if (k2 >= STATIC_KMIN) { unsigned int p = atomicAdd(&lcnt, 1u); if (p < CH_CAP) loc[p] = ((unsigned long long)k2 << 32) | (0xFFFFFFFFu - (base + 2u)); }
        if (k3 >= STATIC_KMIN) { unsigned int p = atomicAdd(&lcnt, 1u); if (p < CH_CAP) loc[p] = ((unsigned long long)k3 << 32) | (0xFFFFFFFFu - (base + 3u)); }
    }
    if (b == 0) {
        const float* p = obj + (size_t)img * A;
        for (int i = (nvec << 2) + t; i < A; i += 256) {
            unsigned int k = fkey(p[i]);
            if (k >= STATIC_KMIN) { unsigned int q = atomicAdd(&lcnt, 1u); if (q < CH_CAP) loc[q] = ((unsigned long long)k << 32) | (0xFFFFFFFFu - (unsigned int)i); }
        }
    }
    __syncthreads();
    if (t == 0) bcnt[img * NCH + b] = lcnt;          // raw count (overflow detectable)
    unsigned int n = min(lcnt, (unsigned int)CH_CAP);
    unsigned long long* dst = cand + (size_t)img * CAND_TOT + (size_t)b * CH_CAP;
    for (unsigned int i = t; i < n; i += 256) dst[i] = loc[i];
}

// fused: (optional exact fallback) + gather + bitonic sort 2048 + device-scope flag sync
// + rank-merge vs other 3 segments + decode/clip. 4 blocks/image, all co-resident (32 blocks).
__global__ __launch_bounds__(1024) void k_sortmerge(
    const float* __restrict__ obj, const float* __restrict__ deltas, const float* __restrict__ anchors,
    unsigned long long* __restrict__ cand, const unsigned int* __restrict__ bcnt,
    unsigned long long* __restrict__ srt, unsigned int* __restrict__ done,
    float* __restrict__ boxes, float* __restrict__ scores, unsigned int* __restrict__ valid, int A) {
    __shared__ unsigned long long sb[3 * SEG];    // 48 KB: sort buf (phase A) / 3 other segments (phase B)
    __shared__ unsigned int cnts[NCH];
    __shared__ unsigned int pref[GPS + 1];
    __shared__ unsigned int kth_s, lcnt;
    __shared__ int bad_s;
    const int img = blockIdx.y;
    const int myseg = blockIdx.x;                 // 0..NSORT-1
    const int t = threadIdx.x;

    if (t < NCH) cnts[t] = bcnt[img * NCH + t];
    __syncthreads();
    if (t == 0) {
        int bad = 0; unsigned int tot = 0;
        for (int c = 0; c < NCH; ++c) { unsigned int r = cnts[c]; if (r > CH_CAP) bad = 1; tot += min(r, (unsigned int)CH_CAP); }
        for (int g = 0; g < NSORT; ++g) {
            unsigned int s = 0;
            for (int c = 0; c < GPS; ++c) s += min(cnts[g * GPS + c], (unsigned int)CH_CAP);
            if (s > (unsigned int)SEG) bad = 1;
        }
        if (tot < (unsigned int)PRE) bad = 1;
        bad_s = bad;
        if (!bad) {
            unsigned int o = 0; pref[0] = 0;
            for (int c = 0; c < GPS; ++c) { o += min(cnts[myseg * GPS + c], (unsigned int)CH_CAP); pref[c + 1] = o; }
        }
    }
    __syncthreads();

    // zero sort buffer region [0, SEG)
    for (int i = t; i < SEG; i += 1024) sb[i] = 0ull;
    __syncthreads();

    if (!bad_s) {
        // gather: 32 threads per chunk
        const int c = t >> 5, lane = t & 31;
        const unsigned int b0 = pref[c], n = pref[c + 1] - pref[c];
        const unsigned long long* src = cand + (size_t)img * CAND_TOT + (size_t)(myseg * GPS + c) * CH_CAP;
        for (unsigned int i = lane; i < n; i += 32) sb[b0 + i] = src[i];
    } else {
        // exact rebuild: histogram -> kth -> compact own index class (i % NSORT == myseg)
        unsigned int* h = (unsigned int*)sb;      // aliases sb[0..2048) as u32[4096]
        for (int i = t; i < 4096; i += 1024) h[i] = 0u;
        __syncthreads();
        const float* p = obj + (size_t)img * A;
        for (int i = t; i < A; i += 1024) atomicAdd(&h[fkey(p[i]) >> 20], 1u);
        __syncthreads();
        if (t == 0) {
            unsigned int run = 0, kb = 0;
            for (int b = 4095; b >= 0; --b) { run += h[b]; if (run >= (unsigned int)PRE) { kb = (unsigned int)b; break; } }
            kth_s = kb << 20;
        }
        __syncthreads();
        for (int i = t; i < SEG; i += 1024) sb[i] = 0ull;   // clear hist region -> padding
        if (t == 0) lcnt = 0u;
        __syncthreads();
        for (int i = t; i < A; i += 1024) {
            unsigned int k = fkey(p[i]);
            if (k >= kth_s && (i & (NSORT - 1)) == myseg) {
                unsigned int q = atomicAdd(&lcnt, 1u);
                if (q < (unsigned int)SEG)
                    sb[q] = ((unsigned long long)k << 32) | (0xFFFFFFFFu - (unsigned int)i);
            }
        }
    }
    __syncthreads();

    // bitonic sort sb[0..SEG) descending (keys unique: key<<32 | inverted idx)
    for (int k = 2; k <= SEG; k <<= 1) {
        for (int j = k >> 1; j > 0; j >>= 1) {
            for (int i = t; i < SEG; i += 1024) {
                int l = i ^ j;
                if (l > i) {
                    unsigned long long a = sb[i], b = sb[l];
                    bool sw = ((i & k) == 0) ? (a < b) : (a > b);
                    if (sw) { sb[i] = b; sb[l] = a; }
                }
            }
            __syncthreads();
        }
    }

    // publish own segment, then device-scope sync with the other 3 blocks of this image
    unsigned long long* seg_out = srt + (size_t)img * CAND_MAX + (size_t)myseg * SEG;
    for (int i = t; i < SEG; i += 1024) seg_out[i] = sb[i];
    __syncthreads();
    unsigned int* dn = done + img * 32;
    if (t == 0) {
        __threadfence();                           // make segment visible device-wide
        atomicAdd(dn, 1u);
        while (atomicAdd(dn, 0u) < (unsigned int)NSORT) __builtin_amdgcn_s_sleep(8);
    }
    __syncthreads();
    __threadfence();                               // acquire: see other segments

    // load the other 3 segments into LDS
    const unsigned long long* simg = srt + (size_t)img * CAND_MAX;
    {
        int q = 0;
        for (int s2 = 0; s2 < NSORT; ++s2) {
            if (s2 == myseg) continue;
            const unsigned long long* src = simg + (size_t)s2 * SEG;
            for (int i = t; i < SEG; i += 1024) sb[q * SEG + i] = src[i];
            ++q;
        }
    }
    __syncthreads();

    // rank own elements vs other segments; decode ranks < PRE
    const unsigned long long* own = simg + (size_t)myseg * SEG;
    for (int e2 = t; e2 < SEG; e2 += 1024) {
        unsigned long long v = own[e2];
        if (v == 0ull) continue;                   // padding
        int rank = e2;
#pragma unroll
        for (int q = 0; q < NSORT - 1; ++q) {
            int lo = 0, hi = SEG;
            const unsigned long long* seg = sb + q * SEG;
            while (lo < hi) {                      // count elements > v (desc order)
                int mid = (lo + hi) >> 1;
                if (seg[mid] > v) lo = mid + 1; else hi = mid;
            }
            rank += lo;
        }
        if (rank >= PRE) continue;
        unsigned int idx = 0xFFFFFFFFu - (unsigned int)(v & 0xFFFFFFFFull);
        float logit = inv_fkey((unsigned int)(v >> 32));
        float4 d = ((const float4*)deltas)[(size_t)img * A + idx];
        float4 a = ((const float4*)anchors)[idx];
        float wa = a.z - a.x, ha = a.w - a.y;
        float cxa = a.x + 0.5f * wa, cya = a.y + 0.5f * ha;
        float dw = fminf(d.z, BBOX_CLIP_F), dh = fminf(d.w, BBOX_CLIP_F);
        float pcx = d.x * wa + cxa, pcy = d.y * ha + cya;
        float pw = expf(dw) * wa, ph = expf(dh) * ha;
        float x1 = fminf(fmaxf(pcx - 0.5f * pw, 0.0f), IMGW);
        float y1 = fminf(fmaxf(pcy - 0.5f * ph, 0.0f), IMGW);
        float x2 = fminf(fmaxf(pcx + 0.5f * pw, 0.0f), IMGW);
        float y2 = fminf(fmaxf(pcy + 0.5f * ph, 0.0f), IMGW);
        float sc = 1.0f / (1.0f + expf(-logit));
        unsigned int vd = (((x2 - x1) >= 1e-3f) && ((y2 - y1) >= 1e-3f) && (sc > 0.0f)) ? 1u : 0u;
        ((float4*)boxes)[(size_t)img * PRE + rank] = make_float4(x1, y1, x2, y2);
        scores[img * PRE + rank] = sc;
        valid[img * PRE + rank] = vd;
    }
}

// sparse suppression pairs (i<j, IoU>0.7): register-row x LDS-tile, per-block private region
__global__ void k_pairs(const float* __restrict__ boxes, unsigned int* __restrict__ pairs,
                        unsigned int* __restrict__ bpcnt) {
#pragma clang fp contract(off)
    const int img = blockIdx.y;
    const int bid = blockIdx.x;
    const int it = bid >> 3;
    const int jc = bid & 7;
    const int t = threadIdx.x;
    if (jc < it) { if (t == 0) bpcnt[img * NPB + bid] = 0u; return; }
    __shared__ float4 jb[JT];
    __shared__ float jar[JT];
    __shared__ unsigned int lp[PB_CAP];      // 4 KB
    __shared__ unsigned int lcnt;
    if (t == 0) lcnt = 0u;
    const float4* B = (const float4*)(boxes + (size_t)img * PRE * 4);
    const int j0 = jc * JT;
    const int jn = min(JT, PRE - j0);
    if (t < jn) {
        float4 b = B[j0 + t];
        jb[t] = b;
        jar[t] = (b.z - b.x) * (b.w - b.y);
    }
    const int i = it * JT + t;
    const bool row_ok = (i < PRE);
    float x1 = 0, y1 = 0, x2 = 0, y2 = 0, ai = 0;
    if (row_ok) {
        float4 b = B[i];
        x1 = b.x; y1 = b.y; x2 = b.z; y2 = b.w;
        ai = (b.z - b.x) * (b.w - b.y);
    }
    __syncthreads();
    if (row_ok) {
#pragma unroll 4
        for (int jj = 0; jj < jn; ++jj) {
            float4 bj = jb[jj];
            float aj = jar[jj];
            float xx1 = fmaxf(x1, bj.x);
            float yy1 = fmaxf(y1, bj.y);
            float xx2 = fminf(x2, bj.z);
            float yy2 = fminf(y2, bj.w);
            float iw = fmaxf(xx2 - xx1, 0.0f);
            float ih = fmaxf(yy2 - yy1, 0.0f);
            float inter = iw * ih;
            float iou = inter / (ai + aj - inter + 1e-12f);
            int j = j0 + jj;
            if (iou > 0.7f && j > i) {
                unsigned int p = atomicAdd(&lcnt, 1u);
                if (p < PB_CAP) lp[p] = ((unsigned int)i << 11) | (unsigned int)j;
            }
        }
    }
    __syncthreads();
    unsigned int n = min(lcnt, (unsigned int)PB_CAP);
    if (t == 0) bpcnt[img * NPB + bid] = n;
    unsigned int* dst = pairs + ((size_t)img * NPB + bid) * PB_CAP;
    for (unsigned int q = t; q < n; q += blockDim.x) dst[q] = lp[q];
}

// fixpoint greedy NMS (order-free), prefix-scan, write [1000,5]
__global__ __launch_bounds__(1024) void k_final(
    const float* __restrict__ boxes, const float* __restrict__ scores, const unsigned int* __restrict__ valid,
    const unsigned int* __restrict__ pairs, const unsigned int* __restrict__ bpcnt, float* __restrict__ out) {
    __shared__ unsigned int pb[PAIR_CAP];     // 48 KB
    __shared__ unsigned int bp[NPB];
    __shared__ unsigned int ofs[NPB + 1];
    __shared__ unsigned char vld[2048];
    __shared__ unsigned char alive[2048];
    __shared__ unsigned char kill[2048];
    __shared__ unsigned int incl[2048];
    __shared__ int changed;
    const int img = blockIdx.x;
    const int t = threadIdx.x;
    if (t < NPB) bp[t] = min(bpcnt[img * NPB + t], (unsigned int)PB_CAP);
    __syncthreads();
    if (t == 0) {
        unsigned int o = 0; ofs[0] = 0;
        for (int c = 0; c < NPB; ++c) { o += bp[c]; if (o > (unsigned int)PAIR_CAP) o = PAIR_CAP; ofs[c + 1] = o; }
    }
    for (int i = t; i < 2048; i += 1024) {
        unsigned char v = (i < PRE) ? (unsigned char)valid[img * PRE + i] : 0;
        vld[i] = v;
        alive[i] = v;
    }
    __syncthreads();
    for (int c = 0; c < NPB; ++c) {
        unsigned int b0 = ofs[c], n = ofs[c + 1] - ofs[c];
        const unsigned int* src = pairs + ((size_t)img * NPB + c) * PB_CAP;
        for (unsigned int i = t; i < n; i += 1024) pb[b0 + i] = src[i];
    }
    const int np = (int)ofs[NPB];
    __syncthreads();
    for (int iter = 0; iter < 2048; ++iter) {
        if (t == 0) changed = 0;
        for (int i = t; i < 2048; i += 1024) kill[i] = 0;
        __syncthreads();
        for (int e = t; e < np; e += 1024) {
            unsigned int u = pb[e];
            unsigned int i = u >> 11, j = u & 2047u;
            if (alive[i]) kill[j] = 1;             // benign same-value races
        }
        __syncthreads();
        for (int i = t; i < 2048; i += 1024) {
            unsigned char na = (vld[i] && !kill[i]) ? 1 : 0;
            if (na != alive[i]) { alive[i] = na; changed = 1; }
        }
        __syncthreads();
        bool done = (changed == 0);
        __syncthreads();                           // protect 'changed' vs next reset
        if (done) break;
    }
    const int i0 = t, i1 = t + 1024;
    incl[i0] = alive[i0]; incl[i1] = alive[i1];
    __syncthreads();
    for (int d = 1; d < 2048; d <<= 1) {
        unsigned int v0 = (i0 >= d) ? incl[i0 - d] : 0u;
        unsigned int v1 = (i1 >= d) ? incl[i1 - d] : 0u;
        __syncthreads();
        incl[i0] += v0; incl[i1] += v1;
        __syncthreads();
    }
    const unsigned int Nk = incl[2047];
    for (int i = t; i < PRE; i += 1024) {
        int slot = -1;
        float sc = 0.0f;
        if (alive[i]) {
            unsigned int r = incl[i] - 1u;
            if (r < (unsigned int)POST) { slot = (int)r; sc = scores[img * PRE + i]; }
        } else if (Nk < (unsigned int)POST) {
            unsigned int rnk = (unsigned int)i - incl[i];      // non-kept rank (ascending index)
            unsigned int s2 = Nk + rnk;
            if (s2 < (unsigned int)POST) { slot = (int)s2; sc = 0.0f; }
        }
        if (slot >= 0) {
            float4 b = ((const float4*)boxes)[(size_t)img * PRE + i];
            float* o = out + ((size_t)img * POST + slot) * 5;
            o[0] = b.x; o[1] = b.y; o[2] = b.z; o[3] = b.w; o[4] = sc;
        }
    }
}

extern "C" void kernel_launch(void* const* d_in, const int* in_sizes, int n_in,
                              void* d_out, int out_size, void* d_ws, size_t ws_size,
                              hipStream_t stream) {
    const float* obj = (const float*)d_in[0];
    const float* deltas = (const float*)d_in[1];
    const float* anchors = (const float*)d_in[2];
    float* out = (float*)d_out;
    const int A = in_sizes[0] / NIMG;

    char* ws = (char*)d_ws;
    unsigned int* bcnt = (unsigned int*)(ws + OFF_BCNT);
    unsigned int* done = (unsigned int*)(ws + OFF_DONE);
    unsigned int* bpcnt = (unsigned int*)(ws + OFF_BPCNT);
    unsigned long long* cand = (unsigned long long*)(ws + OFF_CAND);
    unsigned long long* srt = (unsigned long long*)(ws + OFF_SRT);
    float* boxes = (float*)(ws + OFF_BOX);
    float* scores = (float*)(ws + OFF_SCORE);
    unsigned int* valid = (unsigned int*)(ws + OFF_VALID);
    unsigned int* pairs = (unsigned int*)(ws + OFF_PAIRS);

    k_compact<<<dim3(NCH, NIMG), dim3(256), 0, stream>>>(obj, cand, bcnt, done, A);
    k_sortmerge<<<dim3(NSORT, NIMG), dim3(1024), 0, stream>>>(obj, deltas, anchors, cand, bcnt, srt, done, boxes, scores, valid, A);
    k_pairs<<<dim3(NPB, NIMG), dim3(256), 0, stream>>>(boxes, pairs, bpcnt);
    k_final<<<dim3(NIMG), dim3(1024), 0, stream>>>(boxes, scores, valid, pairs, bpcnt, out);
}

// Round 7
// 292.661 us; speedup vs baseline: 1.0412x; 1.0412x over previous
//
#include <hip/hip_runtime.h>
#include <cstdint>

#define NIMG 8
#define PRE 2000
#define POST 1000
#define NCH 64                    // candidate chunks per image (one per compact block)
#define CH_CAP 256                // entries per chunk
#define CAND_TOT (NCH*CH_CAP)     // 16384 slots per image
#define NSORT 4                   // sorter blocks per image
#define GPS (NCH/NSORT)           // 16 chunks gathered per sorter block
#define SEG 2048                  // sorted segment length
#define CAND_MAX (NSORT*SEG)      // 8192 candidates usable
#define NPT 36                    // upper-triangle pair tiles per image (8x8 incl. diagonal)
#define PB_CAP 1024               // pairs per tile block
#define PAIR_CAP 12288            // k_final LDS pair cap
#define JT 256                    // pair tile edge
#define IMGW 800.0f
#define BBOX_CLIP_F 4.135166556742356f
// fkey(2.5f): fast-path static threshold. count(logit>=2.5) ~ 6210+-79 per image
// -> >=PRE and group sums <=SEG with >>10 sigma margin. Exact in-kernel fallback otherwise.
#define STATIC_KMIN 0xC0200000u

// workspace layout (bytes) -- no pre-zeroing needed anywhere
#define OFF_BCNT  0
#define OFF_BPCNT (OFF_BCNT + NIMG*NCH*4)
#define OFF_CAND  (OFF_BPCNT + NIMG*64*4)
#define OFF_SRT   (OFF_CAND + (size_t)NIMG*CAND_TOT*8)
#define OFF_BOX   (OFF_SRT + (size_t)NIMG*CAND_MAX*8)
#define OFF_SCORE (OFF_BOX + (size_t)NIMG*PRE*16)
#define OFF_VALID (OFF_SCORE + NIMG*PRE*4)
#define OFF_PAIRS (OFF_VALID + NIMG*PRE*4)

__device__ __forceinline__ unsigned int fkey(float f) {
    unsigned int b = __float_as_uint(f);
    return (b & 0x80000000u) ? ~b : (b | 0x80000000u);   // monotone float->uint
}
__device__ __forceinline__ float inv_fkey(unsigned int k) {
    unsigned int b = (k & 0x80000000u) ? (k ^ 0x80000000u) : ~k;
    return __uint_as_float(b);
}

// single 32MB pass: static-threshold compact into per-block private chunks (no global atomics)
__global__ void k_compact(const float* __restrict__ obj,
                          unsigned long long* __restrict__ cand,
                          unsigned int* __restrict__ bcnt, int A) {
    __shared__ unsigned long long loc[CH_CAP];
    __shared__ unsigned int lcnt;
    const int img = blockIdx.y;
    const int b = blockIdx.x;
    const int t = threadIdx.x;
    if (t == 0) lcnt = 0u;
    __syncthreads();
    const float4* p4 = (const float4*)(obj + (size_t)img * A);
    const int nvec = A >> 2;
    for (int i = b * 256 + t; i < nvec; i += NCH * 256) {
        float4 v = p4[i];
        unsigned int k0 = fkey(v.x), k1 = fkey(v.y), k2 = fkey(v.z), k3 = fkey(v.w);
        unsigned int base = (unsigned int)(i << 2);
        if (k0 >= STATIC_KMIN) { unsigned int p = atomicAdd(&lcnt, 1u); if (p < CH_CAP) loc[p] = ((unsigned long long)k0 << 32) | (0xFFFFFFFFu - base); }
        if (k1 >= STATIC_KMIN) { unsigned int p = atomicAdd(&lcnt, 1u); if (p < CH_CAP) loc[p] = ((unsigned long long)k1 << 32) | (0xFFFFFFFFu - (base + 1u)); }
        if (k2 >= STATIC_KMIN) { unsigned int p = atomicAdd(&lcnt, 1u); if (p < CH_CAP) loc[p] = ((unsigned long long)k2 << 32) | (0xFFFFFFFFu - (base + 2u)); }
        if (k3 >= STATIC_KMIN) { unsigned int p = atomicAdd(&lcnt, 1u); if (p < CH_CAP) loc[p] = ((unsigned long long)k3 << 32) | (0xFFFFFFFFu - (base + 3u)); }
    }
    if (b == 0) {
        const float* p = obj + (size_t)img * A;
        for (int i = (nvec << 2) + t; i < A; i += 256) {
            unsigned int k = fkey(p[i]);
            if (k >= STATIC_KMIN) { unsigned int q = atomicAdd(&lcnt, 1u); if (q < CH_CAP) loc[q] = ((unsigned long long)k << 32) | (0xFFFFFFFFu - (unsigned int)i); }
        }
    }
    __syncthreads();
    if (t == 0) bcnt[img * NCH + b] = lcnt;          // raw count (overflow detectable)
    unsigned int n = min(lcnt, (unsigned int)CH_CAP);
    unsigned long long* dst = cand + (size_t)img * CAND_TOT + (size_t)b * CH_CAP;
    for (unsigned int i = t; i < n; i += 256) dst[i] = loc[i];
}

// gather 16 chunks -> bitonic sort 2048 desc -> sorted segment.
// Integrated exact fallback (histogram rebuild of own index class) if static threshold failed.
__global__ __launch_bounds__(1024) void k_sort(
    const float* __restrict__ obj, const unsigned long long* __restrict__ cand,
    const unsigned int* __restrict__ bcnt, unsigned long long* __restrict__ srt, int A) {
    __shared__ unsigned long long sb[SEG];   // 16 KB; aliased as u32[4096] hist in bad path
    __shared__ unsigned int cnts[NCH];
    __shared__ unsigned int pref[GPS + 1];
    __shared__ unsigned int kth_s, lcnt;
    __shared__ int bad_s;
    const int img = blockIdx.y;
    const int myseg = blockIdx.x;            // 0..NSORT-1
    const int t = threadIdx.x;

    if (t < NCH) cnts[t] = bcnt[img * NCH + t];
    __syncthreads();
    if (t == 0) {
        int bad = 0; unsigned int tot = 0;
        for (int c = 0; c < NCH; ++c) { unsigned int r = cnts[c]; if (r > CH_CAP) bad = 1; tot += min(r, (unsigned int)CH_CAP); }
        for (int g = 0; g < NSORT; ++g) {
            unsigned int s = 0;
            for (int c = 0; c < GPS; ++c) s += min(cnts[g * GPS + c], (unsigned int)CH_CAP);
            if (s > (unsigned int)SEG) bad = 1;
        }
        if (tot < (unsigned int)PRE) bad = 1;
        bad_s = bad;
        if (!bad) {
            unsigned int o = 0; pref[0] = 0;
            for (int c = 0; c < GPS; ++c) { o += min(cnts[myseg * GPS + c], (unsigned int)CH_CAP); pref[c + 1] = o; }
        }
    }
    __syncthreads();
    for (int i = t; i < SEG; i += 1024) sb[i] = 0ull;
    __syncthreads();

    if (!bad_s) {
        // gather: 64 threads per chunk
        const int c = t >> 6, lane = t & 63;
        const unsigned int b0 = pref[c], n = pref[c + 1] - pref[c];
        const unsigned long long* src = cand + (size_t)img * CAND_TOT + (size_t)(myseg * GPS + c) * CH_CAP;
        for (unsigned int i = lane; i < n; i += 64) sb[b0 + i] = src[i];
    } else {
        // exact rebuild: histogram -> kth -> compact own index class (i % NSORT == myseg)
        unsigned int* h = (unsigned int*)sb;      // aliases sb[0..2048) as u32[4096]
        for (int i = t; i < 4096; i += 1024) h[i] = 0u;
        __syncthreads();
        const float* p = obj + (size_t)img * A;
        for (int i = t; i < A; i += 1024) atomicAdd(&h[fkey(p[i]) >> 20], 1u);
        __syncthreads();
        if (t == 0) {
            unsigned int run = 0, kb = 0;
            for (int b = 4095; b >= 0; --b) { run += h[b]; if (run >= (unsigned int)PRE) { kb = (unsigned int)b; break; } }
            kth_s = kb << 20;
        }
        __syncthreads();
        for (int i = t; i < SEG; i += 1024) sb[i] = 0ull;   // clear hist region -> padding
        if (t == 0) lcnt = 0u;
        __syncthreads();
        for (int i = t; i < A; i += 1024) {
            unsigned int k = fkey(p[i]);
            if (k >= kth_s && (i & (NSORT - 1)) == myseg) {
                unsigned int q = atomicAdd(&lcnt, 1u);
                if (q < (unsigned int)SEG)
                    sb[q] = ((unsigned long long)k << 32) | (0xFFFFFFFFu - (unsigned int)i);
            }
        }
    }
    __syncthreads();

    // bitonic sort sb[0..SEG) descending (keys unique: key<<32 | inverted idx)
    for (int k = 2; k <= SEG; k <<= 1) {
        for (int j = k >> 1; j > 0; j >>= 1) {
            for (int i = t; i < SEG; i += 1024) {
                int l = i ^ j;
                if (l > i) {
                    unsigned long long a = sb[i], b = sb[l];
                    bool sw = ((i & k) == 0) ? (a < b) : (a > b);
                    if (sw) { sb[i] = b; sb[l] = a; }
                }
            }
            __syncthreads();
        }
    }
    unsigned long long* dst = srt + (size_t)img * CAND_MAX + (size_t)myseg * SEG;
    for (int i = t; i < SEG; i += 1024) dst[i] = sb[i];
}

// exact global rank via binary search vs the other 3 segments; decode+clip ranks < PRE
__global__ __launch_bounds__(1024) void k_merge_decode(
    const float* __restrict__ deltas, const float* __restrict__ anchors,
    const unsigned long long* __restrict__ srt,
    float* __restrict__ boxes, float* __restrict__ scores, unsigned int* __restrict__ valid, int A) {
    __shared__ unsigned long long sb[CAND_MAX];   // 64 KB
    const int img = blockIdx.y;
    const int myseg = blockIdx.x;                 // 0..3
    const int t = threadIdx.x;
    const unsigned long long* c = srt + (size_t)img * CAND_MAX;
    for (int i = t; i < CAND_MAX; i += 1024) sb[i] = c[i];
    __syncthreads();
    for (int e2 = t; e2 < SEG; e2 += 1024) {
        const int e = (myseg << 11) + e2;
        unsigned long long v = sb[e];
        if (v == 0ull) continue;                  // padding
        int rank = e2;
#pragma unroll
        for (int s = 0; s < 4; ++s) {
            if (s == myseg) continue;
            int lo = 0, hi = SEG;
            const unsigned long long* seg = sb + (s << 11);
            while (lo < hi) {                     // count elements > v (desc order)
                int mid = (lo + hi) >> 1;
                if (seg[mid] > v) lo = mid + 1; else hi = mid;
            }
            rank += lo;
        }
        if (rank >= PRE) continue;
        unsigned int idx = 0xFFFFFFFFu - (unsigned int)(v & 0xFFFFFFFFull);
        float logit = inv_fkey((unsigned int)(v >> 32));
        float4 d = ((const float4*)deltas)[(size_t)img * A + idx];
        float4 a = ((const float4*)anchors)[idx];
        float wa = a.z - a.x, ha = a.w - a.y;
        float cxa = a.x + 0.5f * wa, cya = a.y + 0.5f * ha;
        float dw = fminf(d.z, BBOX_CLIP_F), dh = fminf(d.w, BBOX_CLIP_F);
        float pcx = d.x * wa + cxa, pcy = d.y * ha + cya;
        float pw = expf(dw) * wa, ph = expf(dh) * ha;
        float x1 = fminf(fmaxf(pcx - 0.5f * pw, 0.0f), IMGW);
        float y1 = fminf(fmaxf(pcy - 0.5f * ph, 0.0f), IMGW);
        float x2 = fminf(fmaxf(pcx + 0.5f * pw, 0.0f), IMGW);
        float y2 = fminf(fmaxf(pcy + 0.5f * ph, 0.0f), IMGW);
        float sc = 1.0f / (1.0f + expf(-logit));
        unsigned int vd = (((x2 - x1) >= 1e-3f) && ((y2 - y1) >= 1e-3f) && (sc > 0.0f)) ? 1u : 0u;
        ((float4*)boxes)[(size_t)img * PRE + rank] = make_float4(x1, y1, x2, y2);
        scores[img * PRE + rank] = sc;
        valid[img * PRE + rank] = vd;
    }
}

// sparse suppression pairs (i<j, IoU>0.7): register-row x LDS-tile,
// only the 36 upper-triangle tiles launched; per-block private output region.
__global__ void k_pairs(const float* __restrict__ boxes, unsigned int* __restrict__ pairs,
                        unsigned int* __restrict__ bpcnt) {
#pragma clang fp contract(off)
    const int img = blockIdx.y;
    const int bid = blockIdx.x;              // 0..35 linear upper-triangle index
    int rem = bid, it = 0;
    while (rem >= 8 - it) { rem -= 8 - it; ++it; }   // <=8 scalar iterations
    const int jc = it + rem;                 // it <= jc
    const int t = threadIdx.x;
    __shared__ float4 jb[JT];
    __shared__ float jar[JT];
    __shared__ unsigned int lp[PB_CAP];      // 4 KB
    __shared__ unsigned int lcnt;
    if (t == 0) lcnt = 0u;
    const float4* B = (const float4*)(boxes + (size_t)img * PRE * 4);
    const int j0 = jc * JT;
    const int jn = min(JT, PRE - j0);
    if (t < jn) {
        float4 b = B[j0 + t];
        jb[t] = b;
        jar[t] = (b.z - b.x) * (b.w - b.y);
    }
    const int i = it * JT + t;
    const bool row_ok = (i < PRE);
    float x1 = 0, y1 = 0, x2 = 0, y2 = 0, ai = 0;
    if (row_ok) {
        float4 b = B[i];
        x1 = b.x; y1 = b.y; x2 = b.z; y2 = b.w;
        ai = (b.z - b.x) * (b.w - b.y);
    }
    __syncthreads();
    if (row_ok) {
#pragma unroll 4
        for (int jj = 0; jj < jn; ++jj) {
            float4 bj = jb[jj];
            float aj = jar[jj];
            float xx1 = fmaxf(x1, bj.x);
            float yy1 = fmaxf(y1, bj.y);
            float xx2 = fminf(x2, bj.z);
            float yy2 = fminf(y2, bj.w);
            float iw = fmaxf(xx2 - xx1, 0.0f);
            float ih = fmaxf(yy2 - yy1, 0.0f);
            float inter = iw * ih;
            float iou = inter / (ai + aj - inter + 1e-12f);
            int j = j0 + jj;
            if (iou > 0.7f && j > i) {
                unsigned int p = atomicAdd(&lcnt, 1u);
                if (p < PB_CAP) lp[p] = ((unsigned int)i << 11) | (unsigned int)j;
            }
        }
    }
    __syncthreads();
    unsigned int n = min(lcnt, (unsigned int)PB_CAP);
    if (t == 0) bpcnt[img * 64 + bid] = n;
    unsigned int* dst = pairs + ((size_t)img * NPT + bid) * PB_CAP;
    for (unsigned int q = t; q < n; q += blockDim.x) dst[q] = lp[q];
}

// fixpoint greedy NMS (order-free), prefix-scan, write [1000,5]
__global__ __launch_bounds__(1024) void k_final(
    const float* __restrict__ boxes, const float* __restrict__ scores, const unsigned int* __restrict__ valid,
    const unsigned int* __restrict__ pairs, const unsigned int* __restrict__ bpcnt, float* __restrict__ out) {
    __shared__ unsigned int pb[PAIR_CAP];     // 48 KB
    __shared__ unsigned int bp[NPT];
    __shared__ unsigned int ofs[NPT + 1];
    __shared__ unsigned char vld[2048];
    __shared__ unsigned char alive[2048];
    __shared__ unsigned char kill[2048];
    __shared__ unsigned int incl[2048];
    __shared__ int changed;
    const int img = blockIdx.x;
    const int t = threadIdx.x;
    if (t < NPT) bp[t] = min(bpcnt[img * 64 + t], (unsigned int)PB_CAP);
    __syncthreads();
    if (t == 0) {
        unsigned int o = 0; ofs[0] = 0;
        for (int c = 0; c < NPT; ++c) { o += bp[c]; if (o > (unsigned int)PAIR_CAP) o = PAIR_CAP; ofs[c + 1] = o; }
    }
    for (int i = t; i < 2048; i += 1024) {
        unsigned char v = (i < PRE) ? (unsigned char)valid[img * PRE + i] : 0;
        vld[i] = v;
        alive[i] = v;
    }
    __syncthreads();
    for (int c = 0; c < NPT; ++c) {
        unsigned int b0 = ofs[c], n = ofs[c + 1] - ofs[c];
        const unsigned int* src = pairs + ((size_t)img * NPT + c) * PB_CAP;
        for (unsigned int i = t; i < n; i += 1024) pb[b0 + i] = src[i];
    }
    const int np = (int)ofs[NPT];
    __syncthreads();
    for (int iter = 0; iter < 2048; ++iter) {
        if (t == 0) changed = 0;
        for (int i = t; i < 2048; i += 1024) kill[i] = 0;
        __syncthreads();
        for (int e = t; e < np; e += 1024) {
            unsigned int u = pb[e];
            unsigned int i = u >> 11, j = u & 2047u;
            if (alive[i]) kill[j] = 1;             // benign same-value races
        }
        __syncthreads();
        for (int i = t; i < 2048; i += 1024) {
            unsigned char na = (vld[i] && !kill[i]) ? 1 : 0;
            if (na != alive[i]) { alive[i] = na; changed = 1; }
        }
        __syncthreads();
        bool done = (changed == 0);
        __syncthreads();                           // protect 'changed' vs next reset
        if (done) break;
    }
    const int i0 = t, i1 = t + 1024;
    incl[i0] = alive[i0]; incl[i1] = alive[i1];
    __syncthreads();
    for (int d = 1; d < 2048; d <<= 1) {
        unsigned int v0 = (i0 >= d) ? incl[i0 - d] : 0u;
        unsigned int v1 = (i1 >= d) ? incl[i1 - d] : 0u;
        __syncthreads();
        incl[i0] += v0; incl[i1] += v1;
        __syncthreads();
    }
    const unsigned int Nk = incl[2047];
    for (int i = t; i < PRE; i += 1024) {
        int slot = -1;
        float sc = 0.0f;
        if (alive[i]) {
            unsigned int r = incl[i] - 1u;
            if (r < (unsigned int)POST) { slot = (int)r; sc = scores[img * PRE + i]; }
        } else if (Nk < (unsigned int)POST) {
            unsigned int rnk = (unsigned int)i - incl[i];      // non-kept rank (ascending index)
            unsigned int s2 = Nk + rnk;
            if (s2 < (unsigned int)POST) { slot = (int)s2; sc = 0.0f; }
        }
        if (slot >= 0) {
            float4 b = ((const float4*)boxes)[(size_t)img * PRE + i];
            float* o = out + ((size_t)img * POST + slot) * 5;
            o[0] = b.x; o[1] = b.y; o[2] = b.z; o[3] = b.w; o[4] = sc;
        }
    }
}

extern "C" void kernel_launch(void* const* d_in, const int* in_sizes, int n_in,
                              void* d_out, int out_size, void* d_ws, size_t ws_size,
                              hipStream_t stream) {
    const float* obj = (const float*)d_in[0];
    const float* deltas = (const float*)d_in[1];
    const float* anchors = (const float*)d_in[2];
    float* out = (float*)d_out;
    const int A = in_sizes[0] / NIMG;

    char* ws = (char*)d_ws;
    unsigned int* bcnt = (unsigned int*)(ws + OFF_BCNT);
    unsigned int* bpcnt = (unsigned int*)(ws + OFF_BPCNT);
    unsigned long long* cand = (unsigned long long*)(ws + OFF_CAND);
    unsigned long long* srt = (unsigned long long*)(ws + OFF_SRT);
    float* boxes = (float*)(ws + OFF_BOX);
    float* scores = (float*)(ws + OFF_SCORE);
    unsigned int* valid = (unsigned int*)(ws + OFF_VALID);
    unsigned int* pairs = (unsigned int*)(ws + OFF_PAIRS);

    k_compact<<<dim3(NCH, NIMG), dim3(256), 0, stream>>>(obj, cand, bcnt, A);
    k_sort<<<dim3(NSORT, NIMG), dim3(1024), 0, stream>>>(obj, cand, bcnt, srt, A);
    k_merge_decode<<<dim3(NSORT, NIMG), dim3(1024), 0, stream>>>(deltas, anchors, srt, boxes, scores, valid, A);
    k_pairs<<<dim3(NPT, NIMG), dim3(256), 0, stream>>>(boxes, pairs, bpcnt);
    k_final<<<dim3(NIMG), dim3(1024), 0, stream>>>(boxes, scores, valid, pairs, bpcnt, out);
}